// Round 8
// baseline (137.422 us; speedup 1.0000x reference)
//
#include <hip/hip_runtime.h>

#define VOCAB 10000
#define EMB   16
#define HID   32
#define BATCH 4096
#define TLEN  512

typedef float v2f __attribute__((ext_vector_type(2)));
typedef float v4f __attribute__((ext_vector_type(4)));

// ---------------------------------------------------------------------------
// Kernel 1: P[v][j] = b[j] + sum_e emb[v][e] * Wx[e][j]   (fp32 table in ws)
// ---------------------------------------------------------------------------
__global__ __launch_bounds__(256) void rnn_proj(
    const float* __restrict__ emb, const float* __restrict__ Wx,
    const float* __restrict__ bias, float* __restrict__ P)
{
    int tid = blockIdx.x * 256 + threadIdx.x;
    if (tid >= VOCAB * HID) return;
    int v = tid >> 5;
    int j = tid & 31;
    float acc = bias[j];
    const float* ev = emb + v * EMB;
#pragma unroll
    for (int e = 0; e < EMB; ++e) {
        acc = fmaf(ev[e], Wx[e * HID + j], acc);
    }
    P[tid] = acc;
}

// ---------------------------------------------------------------------------
// Kernel 2: batch-packed K-split scan. Wave = 32 j-lanes x 2 k-halves; each
// lane processes TWO batches (b0,b1) packed as float2 -> v_pk_fma_f32.
// The fixed per-step overhead (P addressing, token pipeline, tanh, LDS
// write, pipeline moves) is shared across 2 batches, attacking the ~73
// instr/batch-step overhead that r3..r7 all pinned at.
// h stored interleaved in LDS: h2[j] = {h_j(b0), h_j(b1)} (wave-private,
// no barriers). 2048 waves = 2/SIMD; waves_per_eu(2,2) -> 256-VGPR budget.
// ---------------------------------------------------------------------------
__global__ __launch_bounds__(256)
__attribute__((amdgpu_waves_per_eu(2, 2)))
void rnn_scan(
    const int*   __restrict__ x,   const float* __restrict__ P,
    const float* __restrict__ Wh,  const float* __restrict__ Wd,
    const float* __restrict__ bd,  float* __restrict__ out)
{
    __shared__ v2f h2[4][HID];                  // 256 B per wave

    const int lane = threadIdx.x & 63;
    const int wave = threadIdx.x >> 6;
    const int j    = lane & 31;
    const int kh   = lane >> 5;                 // k-half: i in [kh*16, kh*16+16)
    const int b0   = (blockIdx.x * 4 + wave) * 2;

    // w2[s] = Wh[kh*16+s][j] duplicated into both components
    v2f w2[16];
#pragma unroll
    for (int s = 0; s < 16; ++s) {
        float w = Wh[(kh * 16 + s) * HID + j];
        w2[s] = (v2f){w, w};
    }

    h2[wave][j] = (v2f){0.0f, 0.0f};            // h0 (2 lanes same addr+value: ok)

    const int* xb0 = x + b0 * TLEN;
    const int* xb1 = xb0 + TLEN;

    // pipeline: pA = P(t), pB = P(t+1), tokA/B = token(t+2)
    int tokA = xb0[2], tokB = xb1[2];
    v2f pA = (v2f){ P[xb0[0] * HID + j], P[xb1[0] * HID + j] };
    v2f pB = (v2f){ P[xb0[1] * HID + j], P[xb1[1] * HID + j] };

    // this lane's 16 i-values x 2 batches = 8 float4 reads
    const v4f* hbase = (const v4f*)(&h2[wave][0]) + kh * 8;
    const float TWO_LOG2E = 2.8853900817779268f;

    v2f h = (v2f){0.0f, 0.0f};

    for (int t = 0; t < TLEN; ++t) {
        int ti  = (t + 3 < TLEN) ? (t + 3) : (TLEN - 1);
        int tA3 = xb0[ti], tB3 = xb1[ti];
        v2f pC  = (v2f){ P[tokA * HID + j], P[tokB * HID + j] };

        // half-dot for 2 batches: 16 pk_fma, 4 chains of depth 4
        v2f a0 = (v2f){0,0}, a1 = (v2f){0,0}, a2 = (v2f){0,0}, a3 = (v2f){0,0};
#pragma unroll
        for (int q = 0; q < 4; ++q) {
            v4f u = hbase[2 * q];               // i = kh*16+4q, +1 (x2 batches)
            v4f v = hbase[2 * q + 1];           // i = kh*16+4q+2, +3
            a0 = __builtin_elementwise_fma((v2f){u.x, u.y}, w2[4 * q + 0], a0);
            a1 = __builtin_elementwise_fma((v2f){u.z, u.w}, w2[4 * q + 1], a1);
            a2 = __builtin_elementwise_fma((v2f){v.x, v.y}, w2[4 * q + 2], a2);
            a3 = __builtin_elementwise_fma((v2f){v.z, v.w}, w2[4 * q + 3], a3);
        }
        v2f part = (a0 + a1) + (a2 + a3);

        // combine the two k-halves (partner lane = lane ^ 32)
        v2f other;
        other.x = __shfl_xor(part.x, 32, 64);
        other.y = __shfl_xor(part.y, 32, 64);
        v2f z = pA + part + other;

        // tanh(z) = 1 - 2/(e^{2z}+1); saturates cleanly
        float e0 = __builtin_amdgcn_exp2f(z.x * TWO_LOG2E);
        float e1 = __builtin_amdgcn_exp2f(z.y * TWO_LOG2E);
        float r0 = __builtin_amdgcn_rcpf(e0 + 1.0f);
        float r1 = __builtin_amdgcn_rcpf(e1 + 1.0f);
        h.x = fmaf(-2.0f, r0, 1.0f);
        h.y = fmaf(-2.0f, r1, 1.0f);

        h2[wave][j] = h;                        // visible to this wave next iter

        pA = pB; pB = pC; tokA = tA3; tokB = tB3;
    }

    // out[b] = sigmoid(sum_j h_j * Wd[j] + bd) for both packed batches
    float wd = Wd[j];
    float s0 = h.x * wd, s1 = h.y * wd;
#pragma unroll
    for (int off = 16; off > 0; off >>= 1) {
        s0 += __shfl_xor(s0, off, 32);
        s1 += __shfl_xor(s1, off, 32);
    }
    if (lane == 0) {
        float bdv = bd[0];
        out[b0]     = 1.0f / (1.0f + __expf(-(s0 + bdv)));
        out[b0 + 1] = 1.0f / (1.0f + __expf(-(s1 + bdv)));
    }
}

// ---------------------------------------------------------------------------
extern "C" void kernel_launch(void* const* d_in, const int* in_sizes, int n_in,
                              void* d_out, int out_size, void* d_ws, size_t ws_size,
                              hipStream_t stream)
{
    const int*   x   = (const int*)  d_in[0];
    const float* emb = (const float*)d_in[1];
    const float* Wx  = (const float*)d_in[2];
    const float* Wh  = (const float*)d_in[3];
    const float* bia = (const float*)d_in[4];
    const float* Wd  = (const float*)d_in[5];
    const float* bd  = (const float*)d_in[6];
    float* out = (float*)d_out;

    float* P = (float*)d_ws;                    // VOCAB*HID*4 = 1.28 MB

    rnn_proj<<<(VOCAB * HID + 255) / 256, 256, 0, stream>>>(emb, Wx, bia, P);
    rnn_scan<<<BATCH / 8, 256, 0, stream>>>(x, P, Wh, Wd, bd, out);
}